// Round 8
// baseline (1673.626 us; speedup 1.0000x reference)
//
#include <hip/hip_runtime.h>
#include <stdint.h>

typedef unsigned short u16;
typedef unsigned int u32;
typedef unsigned long long u64;
typedef short v8s __attribute__((ext_vector_type(8)));
typedef float v4f __attribute__((ext_vector_type(4)));

__device__ __forceinline__ float bf2f(u16 u) {
  union { u32 i; float f; } c; c.i = ((u32)u) << 16; return c.f;
}
__device__ __forceinline__ u16 f2bf(float f) {
  u32 x = __float_as_uint(f);
  u32 r = (x + 0x7fffu + ((x >> 16) & 1u)) >> 16;
  return (u16)r;
}

// ---------------- mask packing: adj [4096][4096] int -> bitmask [4096][64] u64
__global__ __launch_bounds__(256) void k_pack_mask(const int* __restrict__ adj,
                                                   u64* __restrict__ maskb) {
  int gid = blockIdx.x * 256 + threadIdx.x;
  int word = gid >> 6;
  int lane = threadIdx.x & 63;
  int v = adj[(size_t)word * 64 + lane];
  u64 b = __ballot(v > 0);
  if (lane == 0) maskb[word] = b;
}

// ---------------- fused lin1+lin2: x[4096][128] (f32) -> h2[4096][64] (bf16)
__global__ __launch_bounds__(64) void k_lin12(const float* __restrict__ x,
    const float* __restrict__ w1, const float* __restrict__ b1,
    const float* __restrict__ w2, const float* __restrict__ b2,
    u16* __restrict__ h2) {
  __shared__ float xr[128];
  __shared__ float h1r[64];
  int i = blockIdx.x, t = threadIdx.x;
  xr[t] = x[i * 128 + t];
  xr[t + 64] = x[i * 128 + 64 + t];
  __syncthreads();
  float a1 = b1[t];
  for (int k = 0; k < 128; ++k) a1 += xr[k] * w1[k * 64 + t];
  h1r[t] = a1;
  __syncthreads();
  float a2 = b2[t];
  for (int k = 0; k < 64; ++k) a2 += h1r[k] * w2[k * 64 + t];
  h2[i * 64 + t] = f2bf(a2);
}

// ---------------- transpose+cast: W [K][F] f32 -> WT [F][K] bf16
__global__ __launch_bounds__(256) void k_transpose(const float* __restrict__ W,
                                                   u16* __restrict__ WT,
                                                   int K, int F, int total) {
  int idx = blockIdx.x * 256 + threadIdx.x;
  if (idx >= total) return;
  int k = idx / F;
  int f = idx - k * F;
  WT[(size_t)f * K + k] = f2bf(W[idx]);
}

// ---------------- bf16 GEMM  D[m][n] = sum_k A[m][k]*B[n][k]  (both k-contiguous)
__global__ __launch_bounds__(256) void k_gemm_bt(const u16* __restrict__ A,
    const u16* __restrict__ B, u16* __restrict__ D, int M, int Nn, int K) {
  __shared__ u16 As[128 * 64];
  __shared__ u16 Bs[128 * 64];
  const int tid = threadIdx.x, wv = tid >> 6, lane = tid & 63;
  const int tile_n = blockIdx.x * 128, tile_m = blockIdx.y * 128;
  const int lr = lane & 15, lq = lane >> 4;
  const int wr = wv >> 1, wc = wv & 1;
  const int srow = lane >> 3, scol = (lane & 7) * 8;
  v4f acc[4][4] = {};
  for (int kb = 0; kb < K; kb += 64) {
    uint4 ra[4], rb4[4];
#pragma unroll
    for (int r = 0; r < 4; ++r) {
      int rowi = wv * 32 + r * 8 + srow;
      ra[r] = *(const uint4*)(A + (size_t)(tile_m + rowi) * K + kb + scol);
      rb4[r] = *(const uint4*)(B + (size_t)(tile_n + rowi) * K + kb + scol);
    }
#pragma unroll
    for (int r = 0; r < 4; ++r) {
      int rowi = wv * 32 + r * 8 + srow;
      *(uint4*)&As[rowi * 64 + scol] = ra[r];
      *(uint4*)&Bs[rowi * 64 + scol] = rb4[r];
    }
    __syncthreads();
#pragma unroll
    for (int kk = 0; kk < 64; kk += 32) {
      v8s af[4], bfr[4];
#pragma unroll
      for (int it = 0; it < 4; ++it)
        af[it] = *(const v8s*)&As[(wr * 64 + it * 16 + lr) * 64 + kk + lq * 8];
#pragma unroll
      for (int ft = 0; ft < 4; ++ft)
        bfr[ft] = *(const v8s*)&Bs[(wc * 64 + ft * 16 + lr) * 64 + kk + lq * 8];
#pragma unroll
      for (int it = 0; it < 4; ++it)
#pragma unroll
        for (int ft = 0; ft < 4; ++ft)
          acc[it][ft] = __builtin_amdgcn_mfma_f32_16x16x32_bf16(af[it], bfr[ft], acc[it][ft], 0, 0, 0);
    }
    __syncthreads();
  }
#pragma unroll
  for (int it = 0; it < 4; ++it)
#pragma unroll
    for (int ft = 0; ft < 4; ++ft)
#pragma unroll
      for (int r = 0; r < 4; ++r) {
        int mrow = tile_m + wr * 64 + it * 16 + lq * 4 + r;
        int ncol = tile_n + wc * 64 + ft * 16 + lr;
        D[(size_t)mrow * Nn + ncol] = f2bf(acc[it][ft][r]);
      }
}

// ---------------- wa[h][2][Fin] = W[h] @ a[h] halves (all f32)
__global__ __launch_bounds__(256) void k_wa(const float* __restrict__ W,
    const float* __restrict__ a, float* __restrict__ wa, int Fin, int F, int total) {
  int idx = blockIdx.x * blockDim.x + threadIdx.x;
  if (idx >= total) return;
  int h = idx / (2 * Fin);
  int r = idx - h * 2 * Fin;
  int which = r / Fin;
  int k = r - which * Fin;
  const float* Wh = W + (size_t)h * Fin * F + (size_t)k * F;
  const float* ah = a + (size_t)h * 2 * F + which * F;
  float sacc = 0.0f;
  for (int f = 0; f < F; ++f) sacc += Wh[f] * ah[f];
  wa[idx] = sacc;
}

// ---------------- s[h][j], t[h][j] = Hin[j] . wa_src/dst  (Hin bf16)
__global__ __launch_bounds__(256) void k_st2(const u16* __restrict__ Hin,
    const float* __restrict__ wa, int Fin, float* __restrict__ s, float* __restrict__ t) {
  int h = blockIdx.y;
  int row = blockIdx.x * 4 + (threadIdx.x >> 6);
  int lane = threadIdx.x & 63;
  const float* wsrc = wa + (size_t)h * 2 * Fin;
  const float* wdst = wsrc + Fin;
  const u16* hr = Hin + (size_t)row * Fin;
  float ps = 0.0f, pt = 0.0f;
  for (int k = lane; k < Fin; k += 64) {
    float v = bf2f(hr[k]);
    ps += v * wsrc[k];
    pt += v * wdst[k];
  }
#pragma unroll
  for (int o = 32; o; o >>= 1) { ps += __shfl_xor(ps, o); pt += __shfl_xor(pt, o); }
  if (lane == 0) { s[h * 4096 + row] = ps; t[h * 4096 + row] = pt; }
}

// ---------------- per-row softmax stats: m_i, 1/l_i
__global__ __launch_bounds__(256) void k_rowstats(const u64* __restrict__ maskb,
    const float* __restrict__ s, const float* __restrict__ t,
    float* __restrict__ m, float* __restrict__ linv) {
  int h = blockIdx.y;
  int row = blockIdx.x * 4 + (threadIdx.x >> 6);
  int lane = threadIdx.x & 63;
  const float* tb = t + h * 4096;
  const u64* mrow = maskb + (size_t)row * 64;
  float tmax = -INFINITY;
  for (int q = 0; q < 64; ++q) {
    u64 w = mrow[q];
    float tv = tb[q * 64 + lane];
    if ((w >> lane) & 1ull) tmax = fmaxf(tmax, tv);
  }
#pragma unroll
  for (int o = 32; o; o >>= 1) tmax = fmaxf(tmax, __shfl_xor(tmax, o));
  float si = s[h * 4096 + row];
  float e0 = si + tmax;
  float mi = fmaxf(e0, 0.2f * e0);
  if (tmax == -INFINITY) mi = 0.0f;
  float sum = 0.0f;
  for (int q = 0; q < 64; ++q) {
    u64 w = mrow[q];
    float e = si + tb[q * 64 + lane];
    e = fmaxf(e, 0.2f * e) - mi;
    float p = __expf(e);
    sum += ((w >> lane) & 1ull) ? p : 0.0f;
  }
#pragma unroll
  for (int o = 32; o; o >>= 1) sum += __shfl_xor(sum, o);
  if (lane == 0) {
    m[h * 4096 + row] = mi;
    linv[h * 4096 + row] = sum > 0.0f ? 1.0f / sum : 0.0f;
  }
}

// ---------------- masked-softmax aggregation: out[i][f] = (1/l_i) sum_j p_ij HpT[f][j]
// writes bf16 (outB) when write_f32==0, else f32 (outF) — final layer output is f32
__global__ __launch_bounds__(256) void k_agg(const u16* __restrict__ hpT,
    const u64* __restrict__ maskb, const float* __restrict__ s, const float* __restrict__ t,
    const float* __restrict__ m, const float* __restrict__ linv,
    u16* __restrict__ outB, float* __restrict__ outF,
    int out_ld, int do_relu, int write_f32) {
  __shared__ u16 Bt[256 * 64];
  __shared__ u16 Pt[64 * 72];
  __shared__ float linv_sh[64];

  const int tid = threadIdx.x;
  const int wv = tid >> 6;
  const int lane = tid & 63;
  const int i0 = blockIdx.x * 64;
  const int gy = blockIdx.y;

  const u16* hb = hpT + (size_t)gy * 256 * 4096;

  if (tid < 64) linv_sh[tid] = linv[i0 + tid];

  const int il = tid >> 2;
  const int jc = (tid & 3) * 16;
  const float si = s[i0 + il];
  const float mi = m[i0 + il];
  const u64* mrow = maskb + (size_t)(i0 + il) * 64;

  const int lr = lane & 15;
  const int lq = lane >> 4;
  const int srow = lane >> 3;
  const int scol = (lane & 7) * 8;

  v4f acc[4][4] = {};

  for (int jb = 0; jb < 64; ++jb) {
    uint4 rv[8];
#pragma unroll
    for (int r = 0; r < 8; ++r) {
      int rowi = wv * 64 + r * 8 + srow;
      rv[r] = *(const uint4*)(hb + (size_t)rowi * 4096 + jb * 64 + scol);
    }
    const u64 w = mrow[jb];
    float tv[16];
    const float4* tp = (const float4*)(t + jb * 64 + jc);
    *(float4*)&tv[0] = tp[0];
    *(float4*)&tv[4] = tp[1];
    *(float4*)&tv[8] = tp[2];
    *(float4*)&tv[12] = tp[3];
    u32 pk[8];
#pragma unroll
    for (int q = 0; q < 8; ++q) {
      float x0 = si + tv[2 * q];
      float e0 = fmaxf(x0, 0.2f * x0) - mi;
      float p0 = __expf(e0);
      p0 = ((w >> (jc + 2 * q)) & 1ull) ? p0 : 0.0f;
      float x1 = si + tv[2 * q + 1];
      float e1 = fmaxf(x1, 0.2f * x1) - mi;
      float p1 = __expf(e1);
      p1 = ((w >> (jc + 2 * q + 1)) & 1ull) ? p1 : 0.0f;
      pk[q] = (u32)f2bf(p0) | ((u32)f2bf(p1) << 16);
    }
#pragma unroll
    for (int r = 0; r < 8; ++r) {
      int rowi = wv * 64 + r * 8 + srow;
      *(uint4*)&Bt[rowi * 64 + scol] = rv[r];
    }
    *(uint4*)&Pt[il * 72 + jc] = *(uint4*)&pk[0];
    *(uint4*)&Pt[il * 72 + jc + 8] = *(uint4*)&pk[4];

    __syncthreads();

#pragma unroll
    for (int kk = 0; kk < 64; kk += 32) {
      v8s af[4], bfr[4];
#pragma unroll
      for (int it = 0; it < 4; ++it)
        af[it] = *(const v8s*)&Pt[(it * 16 + lr) * 72 + kk + lq * 8];
#pragma unroll
      for (int ft = 0; ft < 4; ++ft)
        bfr[ft] = *(const v8s*)&Bt[(wv * 64 + ft * 16 + lr) * 64 + kk + lq * 8];
#pragma unroll
      for (int it = 0; it < 4; ++it)
#pragma unroll
        for (int ft = 0; ft < 4; ++ft)
          acc[it][ft] = __builtin_amdgcn_mfma_f32_16x16x32_bf16(af[it], bfr[ft], acc[it][ft], 0, 0, 0);
    }
    __syncthreads();
  }

  const int colbase = gy * 256 + wv * 64;
#pragma unroll
  for (int it = 0; it < 4; ++it)
#pragma unroll
    for (int ft = 0; ft < 4; ++ft)
#pragma unroll
      for (int r = 0; r < 4; ++r) {
        int ilocal = it * 16 + lq * 4 + r;
        int col = colbase + ft * 16 + lr;
        float v = acc[it][ft][r] * linv_sh[ilocal];
        if (do_relu) v = fmaxf(v, 0.0f);
        if (write_f32)
          outF[(size_t)(i0 + ilocal) * out_ld + col] = v;
        else
          outB[(size_t)(i0 + ilocal) * out_ld + col] = f2bf(v);
      }
}

// ---------------- GroupNorm(1 group over everything) reduce + apply (in place)
__global__ __launch_bounds__(256) void k_gn_reduce(const u16* __restrict__ h4,
                                                   float* __restrict__ accv) {
  const size_t total = (size_t)4096 * 1536 / 8;
  float sm = 0.0f, s2 = 0.0f;
  for (size_t c = (size_t)blockIdx.x * 256 + threadIdx.x; c < total; c += (size_t)gridDim.x * 256) {
    uint4 u = ((const uint4*)h4)[c];
    u16 us[8];
    *(uint4*)us = u;
#pragma unroll
    for (int k = 0; k < 8; ++k) {
      float v = bf2f(us[k]);
      sm += v;
      s2 += v * v;
    }
  }
#pragma unroll
  for (int o = 32; o; o >>= 1) { sm += __shfl_xor(sm, o); s2 += __shfl_xor(s2, o); }
  if ((threadIdx.x & 63) == 0) {
    atomicAdd(&accv[0], sm);
    atomicAdd(&accv[1], s2);
  }
}

__global__ __launch_bounds__(256) void k_gn_apply(const u16* __restrict__ h4,
    const float* __restrict__ accv, const float* __restrict__ gw,
    const float* __restrict__ gb, u16* __restrict__ h5) {
  const float Mc = 4096.0f * 1536.0f;
  float mu = accv[0] * (1.0f / Mc);
  float var = (accv[1] - Mc * mu * mu) * (1.0f / (Mc - 1.0f));
  float rstd = rsqrtf(var + 1e-5f);
  size_t c = (size_t)blockIdx.x * 256 + threadIdx.x;
  uint4 u = ((const uint4*)h4)[c];
  u16 us[8], os[8];
  *(uint4*)us = u;
  int col0 = (int)((c * 8) % 1536);
#pragma unroll
  for (int k = 0; k < 8; ++k) {
    float v = (bf2f(us[k]) - mu) * rstd * gw[col0 + k] + gb[col0 + k];
    os[k] = f2bf(v);
  }
  ((uint4*)h5)[c] = *(uint4*)os;
}

extern "C" void kernel_launch(void* const* d_in, const int* in_sizes, int n_in,
                              void* d_out, int out_size, void* d_ws, size_t ws_size,
                              hipStream_t stream) {
  const float* x = (const float*)d_in[0];
  const int* adj = (const int*)d_in[1];
  const float* lin1_w = (const float*)d_in[2];
  const float* lin1_b = (const float*)d_in[3];
  const float* lin2_w = (const float*)d_in[4];
  const float* lin2_b = (const float*)d_in[5];
  const float* conv1_W = (const float*)d_in[6];
  const float* conv1_a = (const float*)d_in[7];
  const float* att_W = (const float*)d_in[8];
  const float* att_a = (const float*)d_in[9];
  const float* gn_w = (const float*)d_in[10];
  const float* gn_b = (const float*)d_in[11];
  const float* conv2_W = (const float*)d_in[12];
  const float* conv2_a = (const float*)d_in[13];
  float* out = (float*)d_out;   // reference output dtype is float32

  // ---- arena: 23.2 MB (ws_size >= 24 MB verified in R4)
  char* base = (char*)d_ws;
  u64* maskb = (u64*)base;                                  // [0, 2MB)
  u16* hpT = (u16*)(base + (2ull << 20));                   // [2, 6MB)
  u16* hC  = (u16*)(base + (6ull << 20));                   // [6, 18MB) h2, then h4/h5
  u16* h3  = (u16*)(base + (18ull << 20));                  // [18, 22MB)
  u16* wt  = (u16*)(base + (22ull << 20));                  // [22, 22.75MB)
  float* sA = (float*)(base + (22ull << 20) + (768ull << 10));
  float* tA = sA + 6 * 4096;
  float* mA = tA + 6 * 4096;
  float* lA = mA + 6 * 4096;
  float* wab = lA + 6 * 4096;
  float* gacc = wab + 8192;

  hipMemsetAsync(gacc, 0, 16, stream);
  k_pack_mask<<<dim3(65536), dim3(256), 0, stream>>>(adj, maskb);
  k_lin12<<<dim3(4096), dim3(64), 0, stream>>>(x, lin1_w, lin1_b, lin2_w, lin2_b, hC);

  // ---- conv1 (F=512)
  k_transpose<<<dim3(128), dim3(256), 0, stream>>>(conv1_W, wt, 64, 512, 64 * 512);
  k_gemm_bt<<<dim3(32, 4), dim3(256), 0, stream>>>(wt, hC, hpT, 512, 4096, 64);
  k_wa<<<dim3(1), dim3(128), 0, stream>>>(conv1_W, conv1_a, wab, 64, 512, 128);
  k_st2<<<dim3(1024, 1), dim3(256), 0, stream>>>(hC, wab, 64, sA, tA);
  k_rowstats<<<dim3(1024, 1), dim3(256), 0, stream>>>(maskb, sA, tA, mA, lA);
  k_agg<<<dim3(64, 2), dim3(256), 0, stream>>>(hpT, maskb, sA, tA, mA, lA, h3, (float*)0, 512, 1, 0);

  // ---- 6 heads (F=256), per-head proj+agg; stats batched
  k_wa<<<dim3(24), dim3(256), 0, stream>>>(att_W, att_a, wab, 512, 256, 6144);
  k_st2<<<dim3(1024, 6), dim3(256), 0, stream>>>(h3, wab, 512, sA, tA);
  k_rowstats<<<dim3(1024, 6), dim3(256), 0, stream>>>(maskb, sA, tA, mA, lA);
  for (int h = 0; h < 6; ++h) {
    k_transpose<<<dim3(512), dim3(256), 0, stream>>>(att_W + (size_t)h * 512 * 256, wt, 512, 256, 512 * 256);
    k_gemm_bt<<<dim3(32, 2), dim3(256), 0, stream>>>(wt, h3, hpT, 256, 4096, 512);
    k_agg<<<dim3(64, 1), dim3(256), 0, stream>>>(hpT, maskb, sA + h * 4096, tA + h * 4096,
                                                 mA + h * 4096, lA + h * 4096,
                                                 hC + h * 256, (float*)0, 1536, 1, 0);
  }

  // ---- GroupNorm (in place on hC)
  k_gn_reduce<<<dim3(1024), dim3(256), 0, stream>>>(hC, gacc);
  k_gn_apply<<<dim3(3072), dim3(256), 0, stream>>>(hC, gacc, gn_w, gn_b, hC);

  // ---- conv2 (F=256) -> output (FLOAT32)
  k_transpose<<<dim3(1536), dim3(256), 0, stream>>>(conv2_W, wt, 1536, 256, 1536 * 256);
  k_gemm_bt<<<dim3(32, 2), dim3(256), 0, stream>>>(wt, hC, hpT, 256, 4096, 1536);
  k_wa<<<dim3(12), dim3(256), 0, stream>>>(conv2_W, conv2_a, wab, 1536, 256, 3072);
  k_st2<<<dim3(1024, 1), dim3(256), 0, stream>>>(hC, wab, 1536, sA, tA);
  k_rowstats<<<dim3(1024, 1), dim3(256), 0, stream>>>(maskb, sA, tA, mA, lA);
  k_agg<<<dim3(64, 1), dim3(256), 0, stream>>>(hpT, maskb, sA, tA, mA, lA, (u16*)0, out, 256, 0, 1);
}

// Round 9
// 872.824 us; speedup vs baseline: 1.9175x; 1.9175x over previous
//
#include <hip/hip_runtime.h>
#include <stdint.h>

typedef unsigned short u16;
typedef unsigned int u32;
typedef unsigned long long u64;
typedef short v8s __attribute__((ext_vector_type(8)));
typedef float v4f __attribute__((ext_vector_type(4)));

__device__ __forceinline__ float bf2f(u16 u) {
  union { u32 i; float f; } c; c.i = ((u32)u) << 16; return c.f;
}
__device__ __forceinline__ u16 f2bf(float f) {
  u32 x = __float_as_uint(f);
  u32 r = (x + 0x7fffu + ((x >> 16) & 1u)) >> 16;
  return (u16)r;
}

// ---------------- mask packing: adj [4096][4096] int -> bitmask [4096][64] u64
__global__ __launch_bounds__(256) void k_pack_mask(const int* __restrict__ adj,
                                                   u64* __restrict__ maskb) {
  int gid = blockIdx.x * 256 + threadIdx.x;
  int word = gid >> 6;
  int lane = threadIdx.x & 63;
  int v = adj[(size_t)word * 64 + lane];
  u64 b = __ballot(v > 0);
  if (lane == 0) maskb[word] = b;
}

// ---------------- fused lin1+lin2: x[4096][128] (f32) -> h2[4096][64] (bf16)
__global__ __launch_bounds__(64) void k_lin12(const float* __restrict__ x,
    const float* __restrict__ w1, const float* __restrict__ b1,
    const float* __restrict__ w2, const float* __restrict__ b2,
    u16* __restrict__ h2) {
  __shared__ float xr[128];
  __shared__ float h1r[64];
  int i = blockIdx.x, t = threadIdx.x;
  xr[t] = x[i * 128 + t];
  xr[t + 64] = x[i * 128 + 64 + t];
  __syncthreads();
  float a1 = b1[t];
  for (int k = 0; k < 128; ++k) a1 += xr[k] * w1[k * 64 + t];
  h1r[t] = a1;
  __syncthreads();
  float a2 = b2[t];
  for (int k = 0; k < 64; ++k) a2 += h1r[k] * w2[k * 64 + t];
  h2[i * 64 + t] = f2bf(a2);
}

// ---------------- batched transpose+cast: W [Bh][K][F] f32 -> WT [Bh*F][K] bf16
__global__ __launch_bounds__(256) void k_transpose(const float* __restrict__ W,
                                                   u16* __restrict__ WT,
                                                   int K, int F, int total) {
  int idx = blockIdx.x * 256 + threadIdx.x;
  if (idx >= total) return;
  int kf = K * F;
  int h = idx / kf;
  int r = idx - h * kf;
  int k = r / F;
  int f = r - k * F;
  WT[((size_t)h * F + f) * K + k] = f2bf(W[idx]);
}

// ---------------- bf16 GEMM  D[m][n] = sum_k A[m][k]*B[n][k]  (both k-contiguous)
__global__ __launch_bounds__(256) void k_gemm_bt(const u16* __restrict__ A,
    const u16* __restrict__ B, u16* __restrict__ D, int M, int Nn, int K) {
  __shared__ u16 As[128 * 64];
  __shared__ u16 Bs[128 * 64];
  const int tid = threadIdx.x, wv = tid >> 6, lane = tid & 63;
  const int tile_n = blockIdx.x * 128, tile_m = blockIdx.y * 128;
  const int lr = lane & 15, lq = lane >> 4;
  const int wr = wv >> 1, wc = wv & 1;
  const int srow = lane >> 3, scol = (lane & 7) * 8;
  v4f acc[4][4] = {};
  for (int kb = 0; kb < K; kb += 64) {
    uint4 ra[4], rb4[4];
#pragma unroll
    for (int r = 0; r < 4; ++r) {
      int rowi = wv * 32 + r * 8 + srow;
      ra[r] = *(const uint4*)(A + (size_t)(tile_m + rowi) * K + kb + scol);
      rb4[r] = *(const uint4*)(B + (size_t)(tile_n + rowi) * K + kb + scol);
    }
#pragma unroll
    for (int r = 0; r < 4; ++r) {
      int rowi = wv * 32 + r * 8 + srow;
      *(uint4*)&As[rowi * 64 + scol] = ra[r];
      *(uint4*)&Bs[rowi * 64 + scol] = rb4[r];
    }
    __syncthreads();
#pragma unroll
    for (int kk = 0; kk < 64; kk += 32) {
      v8s af[4], bfr[4];
#pragma unroll
      for (int it = 0; it < 4; ++it)
        af[it] = *(const v8s*)&As[(wr * 64 + it * 16 + lr) * 64 + kk + lq * 8];
#pragma unroll
      for (int ft = 0; ft < 4; ++ft)
        bfr[ft] = *(const v8s*)&Bs[(wc * 64 + ft * 16 + lr) * 64 + kk + lq * 8];
#pragma unroll
      for (int it = 0; it < 4; ++it)
#pragma unroll
        for (int ft = 0; ft < 4; ++ft)
          acc[it][ft] = __builtin_amdgcn_mfma_f32_16x16x32_bf16(af[it], bfr[ft], acc[it][ft], 0, 0, 0);
    }
    __syncthreads();
  }
#pragma unroll
  for (int it = 0; it < 4; ++it)
#pragma unroll
    for (int ft = 0; ft < 4; ++ft)
#pragma unroll
      for (int r = 0; r < 4; ++r) {
        int mrow = tile_m + wr * 64 + it * 16 + lq * 4 + r;
        int ncol = tile_n + wc * 64 + ft * 16 + lr;
        D[(size_t)mrow * Nn + ncol] = f2bf(acc[it][ft][r]);
      }
}

// ---------------- wa[h][2][Fin] = W[h] @ a[h] halves (all f32)
__global__ __launch_bounds__(256) void k_wa(const float* __restrict__ W,
    const float* __restrict__ a, float* __restrict__ wa, int Fin, int F, int total) {
  int idx = blockIdx.x * blockDim.x + threadIdx.x;
  if (idx >= total) return;
  int h = idx / (2 * Fin);
  int r = idx - h * 2 * Fin;
  int which = r / Fin;
  int k = r - which * Fin;
  const float* Wh = W + (size_t)h * Fin * F + (size_t)k * F;
  const float* ah = a + (size_t)h * 2 * F + which * F;
  float sacc = 0.0f;
  for (int f = 0; f < F; ++f) sacc += Wh[f] * ah[f];
  wa[idx] = sacc;
}

// ---------------- s[h][j], t[h][j] = Hin[j] . wa_src/dst  (Hin bf16)
__global__ __launch_bounds__(256) void k_st2(const u16* __restrict__ Hin,
    const float* __restrict__ wa, int Fin, float* __restrict__ s, float* __restrict__ t) {
  int h = blockIdx.y;
  int row = blockIdx.x * 4 + (threadIdx.x >> 6);
  int lane = threadIdx.x & 63;
  const float* wsrc = wa + (size_t)h * 2 * Fin;
  const float* wdst = wsrc + Fin;
  const u16* hr = Hin + (size_t)row * Fin;
  float ps = 0.0f, pt = 0.0f;
  for (int k = lane; k < Fin; k += 64) {
    float v = bf2f(hr[k]);
    ps += v * wsrc[k];
    pt += v * wdst[k];
  }
#pragma unroll
  for (int o = 32; o; o >>= 1) { ps += __shfl_xor(ps, o); pt += __shfl_xor(pt, o); }
  if (lane == 0) { s[h * 4096 + row] = ps; t[h * 4096 + row] = pt; }
}

// ---------------- per-row softmax stats: m_i, 1/l_i
__global__ __launch_bounds__(256) void k_rowstats(const u64* __restrict__ maskb,
    const float* __restrict__ s, const float* __restrict__ t,
    float* __restrict__ m, float* __restrict__ linv) {
  int h = blockIdx.y;
  int row = blockIdx.x * 4 + (threadIdx.x >> 6);
  int lane = threadIdx.x & 63;
  const float* tb = t + h * 4096;
  const u64* mrow = maskb + (size_t)row * 64;
  float tmax = -INFINITY;
  for (int q = 0; q < 64; ++q) {
    u64 w = mrow[q];
    float tv = tb[q * 64 + lane];
    if ((w >> lane) & 1ull) tmax = fmaxf(tmax, tv);
  }
#pragma unroll
  for (int o = 32; o; o >>= 1) tmax = fmaxf(tmax, __shfl_xor(tmax, o));
  float si = s[h * 4096 + row];
  float e0 = si + tmax;
  float mi = fmaxf(e0, 0.2f * e0);
  if (tmax == -INFINITY) mi = 0.0f;
  float sum = 0.0f;
  for (int q = 0; q < 64; ++q) {
    u64 w = mrow[q];
    float e = si + tb[q * 64 + lane];
    e = fmaxf(e, 0.2f * e) - mi;
    float p = __expf(e);
    sum += ((w >> lane) & 1ull) ? p : 0.0f;
  }
#pragma unroll
  for (int o = 32; o; o >>= 1) sum += __shfl_xor(sum, o);
  if (lane == 0) {
    m[h * 4096 + row] = mi;
    linv[h * 4096 + row] = sum > 0.0f ? 1.0f / sum : 0.0f;
  }
}

// ---------------- masked-softmax aggregation, 32-row tiles
// grid (128, NY, Z). gy selects 256-col slice of hpT (and head stats via stats_stride).
// Z>1: fp32 atomic partials into outF (no linv); else bf16 direct with linv+relu.
__global__ __launch_bounds__(256) void k_agg(const u16* __restrict__ hpT,
    const u64* __restrict__ maskb, const float* __restrict__ s, const float* __restrict__ t,
    const float* __restrict__ m, const float* __restrict__ linv,
    u16* __restrict__ outB, float* __restrict__ outF,
    int out_ld, int stats_stride, int do_relu, int use_atomic) {
  __shared__ u16 Bt[256 * 64];
  __shared__ u16 Pt[32 * 72];
  __shared__ float linv_sh[32];

  const int tid = threadIdx.x;
  const int wv = tid >> 6;
  const int lane = tid & 63;
  const int i0 = blockIdx.x * 32;
  const int gy = blockIdx.y;

  const u16* hb = hpT + (size_t)gy * 256 * 4096;
  const float* sb = s + gy * stats_stride;
  const float* tb = t + gy * stats_stride;
  const float* mb = m + gy * stats_stride;
  const float* lb = linv + gy * stats_stride;

  if (tid < 32) linv_sh[tid] = lb[i0 + tid];

  const int il = tid >> 3;           // local row 0..31
  const int jc = (tid & 7) * 8;      // 8-wide j chunk
  const float si = sb[i0 + il];
  const float mi = mb[i0 + il];
  const u64* mrow = maskb + (size_t)(i0 + il) * 64;

  const int lr = lane & 15;
  const int lq = lane >> 4;
  const int srow = lane >> 3;
  const int scol = (lane & 7) * 8;

  v4f acc[2][4] = {};

  const int njb = 64 / gridDim.z;
  const int jb0 = blockIdx.z * njb;

  for (int jb = jb0; jb < jb0 + njb; ++jb) {
    uint4 rv[8];
#pragma unroll
    for (int r = 0; r < 8; ++r) {
      int rowi = wv * 64 + r * 8 + srow;
      rv[r] = *(const uint4*)(hb + (size_t)rowi * 4096 + jb * 64 + scol);
    }
    const u64 w = mrow[jb];
    float tv[8];
    const float4* tp = (const float4*)(tb + jb * 64 + jc);
    *(float4*)&tv[0] = tp[0];
    *(float4*)&tv[4] = tp[1];
    u32 pk[4];
#pragma unroll
    for (int q = 0; q < 4; ++q) {
      float x0 = si + tv[2 * q];
      float e0 = fmaxf(x0, 0.2f * x0) - mi;
      float p0 = __expf(e0);
      p0 = ((w >> (jc + 2 * q)) & 1ull) ? p0 : 0.0f;
      float x1 = si + tv[2 * q + 1];
      float e1 = fmaxf(x1, 0.2f * x1) - mi;
      float p1 = __expf(e1);
      p1 = ((w >> (jc + 2 * q + 1)) & 1ull) ? p1 : 0.0f;
      pk[q] = (u32)f2bf(p0) | ((u32)f2bf(p1) << 16);
    }
#pragma unroll
    for (int r = 0; r < 8; ++r) {
      int rowi = wv * 64 + r * 8 + srow;
      *(uint4*)&Bt[rowi * 64 + scol] = rv[r];
    }
    *(uint4*)&Pt[il * 72 + jc] = *(uint4*)&pk[0];

    __syncthreads();

#pragma unroll
    for (int kk = 0; kk < 64; kk += 32) {
      v8s af[2], bfr[4];
#pragma unroll
      for (int it = 0; it < 2; ++it)
        af[it] = *(const v8s*)&Pt[(it * 16 + lr) * 72 + kk + lq * 8];
#pragma unroll
      for (int ft = 0; ft < 4; ++ft)
        bfr[ft] = *(const v8s*)&Bt[(wv * 64 + ft * 16 + lr) * 64 + kk + lq * 8];
#pragma unroll
      for (int it = 0; it < 2; ++it)
#pragma unroll
        for (int ft = 0; ft < 4; ++ft)
          acc[it][ft] = __builtin_amdgcn_mfma_f32_16x16x32_bf16(af[it], bfr[ft], acc[it][ft], 0, 0, 0);
    }
    __syncthreads();
  }

#pragma unroll
  for (int it = 0; it < 2; ++it)
#pragma unroll
    for (int ft = 0; ft < 4; ++ft)
#pragma unroll
      for (int r = 0; r < 4; ++r) {
        int ilocal = it * 16 + lq * 4 + r;
        int col = gy * 256 + wv * 64 + ft * 16 + lr;
        if (use_atomic) {
          atomicAdd(&outF[(size_t)(i0 + ilocal) * out_ld + col], acc[it][ft][r]);
        } else {
          float v = acc[it][ft][r] * linv_sh[ilocal];
          if (do_relu) v = fmaxf(v, 0.0f);
          outB[(size_t)(i0 + ilocal) * out_ld + col] = f2bf(v);
        }
      }
}

// ---------------- finalize j-split partials
__global__ __launch_bounds__(256) void k_fin_bf(const float* __restrict__ outF,
    const float* __restrict__ linv, u16* __restrict__ outB, int F, int do_relu) {
  size_t idx = (size_t)blockIdx.x * 256 + threadIdx.x;
  int row = (int)(idx / F);
  float v = outF[idx] * linv[row];
  if (do_relu) v = fmaxf(v, 0.0f);
  outB[idx] = f2bf(v);
}
__global__ __launch_bounds__(256) void k_fin_f32(float* __restrict__ outF,
    const float* __restrict__ linv, int F) {
  size_t idx = (size_t)blockIdx.x * 256 + threadIdx.x;
  int row = (int)(idx / F);
  outF[idx] *= linv[row];
}

// ---------------- GroupNorm(1 group over everything) reduce + apply (in place)
__global__ __launch_bounds__(256) void k_gn_reduce(const u16* __restrict__ h4,
                                                   float* __restrict__ accv) {
  const size_t total = (size_t)4096 * 1536 / 8;
  float sm = 0.0f, s2 = 0.0f;
  for (size_t c = (size_t)blockIdx.x * 256 + threadIdx.x; c < total; c += (size_t)gridDim.x * 256) {
    uint4 u = ((const uint4*)h4)[c];
    u16 us[8];
    *(uint4*)us = u;
#pragma unroll
    for (int k = 0; k < 8; ++k) {
      float v = bf2f(us[k]);
      sm += v;
      s2 += v * v;
    }
  }
#pragma unroll
  for (int o = 32; o; o >>= 1) { sm += __shfl_xor(sm, o); s2 += __shfl_xor(s2, o); }
  if ((threadIdx.x & 63) == 0) {
    atomicAdd(&accv[0], sm);
    atomicAdd(&accv[1], s2);
  }
}

__global__ __launch_bounds__(256) void k_gn_apply(const u16* __restrict__ h4,
    const float* __restrict__ accv, const float* __restrict__ gw,
    const float* __restrict__ gb, u16* __restrict__ h5) {
  const float Mc = 4096.0f * 1536.0f;
  float mu = accv[0] * (1.0f / Mc);
  float var = (accv[1] - Mc * mu * mu) * (1.0f / (Mc - 1.0f));
  float rstd = rsqrtf(var + 1e-5f);
  size_t c = (size_t)blockIdx.x * 256 + threadIdx.x;
  uint4 u = ((const uint4*)h4)[c];
  u16 us[8], os[8];
  *(uint4*)us = u;
  int col0 = (int)((c * 8) % 1536);
#pragma unroll
  for (int k = 0; k < 8; ++k) {
    float v = (bf2f(us[k]) - mu) * rstd * gw[col0 + k] + gb[col0 + k];
    os[k] = f2bf(v);
  }
  ((uint4*)h5)[c] = *(uint4*)os;
}

extern "C" void kernel_launch(void* const* d_in, const int* in_sizes, int n_in,
                              void* d_out, int out_size, void* d_ws, size_t ws_size,
                              hipStream_t stream) {
  const float* x = (const float*)d_in[0];
  const int* adj = (const int*)d_in[1];
  const float* lin1_w = (const float*)d_in[2];
  const float* lin1_b = (const float*)d_in[3];
  const float* lin2_w = (const float*)d_in[4];
  const float* lin2_b = (const float*)d_in[5];
  const float* conv1_W = (const float*)d_in[6];
  const float* conv1_a = (const float*)d_in[7];
  const float* att_W = (const float*)d_in[8];
  const float* att_a = (const float*)d_in[9];
  const float* gn_w = (const float*)d_in[10];
  const float* gn_b = (const float*)d_in[11];
  const float* conv2_W = (const float*)d_in[12];
  const float* conv2_a = (const float*)d_in[13];
  float* out = (float*)d_out;   // reference output dtype: float32

  // ---- arena, adaptive: big path needs 32.5 MB (6-head batch), small path 23.75 MB
  const bool big = ws_size >= (34ull << 20);
  const int B = big ? 6 : 2;           // heads per batch
  char* base = (char*)d_ws;
  const size_t MB = 1ull << 20;
  u64* maskb = (u64*)base;                                   // 2 MB
  u16* hpT = (u16*)(base + 2 * MB);                          // big 12 / small 4 MB
  u16* hC  = (u16*)(base + (big ? 14 : 6) * MB);             // 12 MB (h4/h5)
  u16* h3  = (u16*)(base + (big ? 26 : 18) * MB);            // 4 MB
  u16* h2  = (u16*)(base + (big ? 30 : 22) * MB);            // 0.5 MB
  u16* wt  = (u16*)(base + (big ? 30 : 22) * MB + 512 * 1024);      // 1.5 MB
  float* sA = (float*)(base + (big ? 32 : 24) * MB);         // stats 0.5 MB
  float* tA = sA + 6 * 4096;
  float* mA = tA + 6 * 4096;
  float* lA = mA + 6 * 4096;
  float* wab = lA + 6 * 4096;
  float* gacc = wab + 8192;
  float* outF1 = (float*)hC;   // conv1 fp32 partials (8 MB) — h4 not yet live

  hipMemsetAsync(gacc, 0, 16, stream);
  hipMemsetAsync(out, 0, (size_t)4096 * 256 * 4, stream);
  hipMemsetAsync(outF1, 0, (size_t)4096 * 512 * 4, stream);

  k_pack_mask<<<dim3(65536), dim3(256), 0, stream>>>(adj, maskb);
  k_lin12<<<dim3(4096), dim3(64), 0, stream>>>(x, lin1_w, lin1_b, lin2_w, lin2_b, h2);

  // ---- conv1 (F=512): j-split Z=2, 512 WGs
  k_transpose<<<dim3(128), dim3(256), 0, stream>>>(conv1_W, wt, 64, 512, 64 * 512);
  k_gemm_bt<<<dim3(32, 4), dim3(256), 0, stream>>>(wt, h2, hpT, 512, 4096, 64);
  k_wa<<<dim3(1), dim3(128), 0, stream>>>(conv1_W, conv1_a, wab, 64, 512, 128);
  k_st2<<<dim3(1024, 1), dim3(256), 0, stream>>>(h2, wab, 64, sA, tA);
  k_rowstats<<<dim3(1024, 1), dim3(256), 0, stream>>>(maskb, sA, tA, mA, lA);
  k_agg<<<dim3(128, 2, 2), dim3(256), 0, stream>>>(hpT, maskb, sA, tA, mA, lA,
                                                   (u16*)0, outF1, 512, 0, 0, 1);
  k_fin_bf<<<dim3(8192), dim3(256), 0, stream>>>(outF1, lA, h3, 512, 1);

  // ---- 6 heads (F=256), batched B at a time; stats batched once
  k_wa<<<dim3(24), dim3(256), 0, stream>>>(att_W, att_a, wab, 512, 256, 6144);
  k_st2<<<dim3(1024, 6), dim3(256), 0, stream>>>(h3, wab, 512, sA, tA);
  k_rowstats<<<dim3(1024, 6), dim3(256), 0, stream>>>(maskb, sA, tA, mA, lA);
  for (int bh = 0; bh < 6; bh += B) {
    k_transpose<<<dim3(B * 512), dim3(256), 0, stream>>>(att_W + (size_t)bh * 512 * 256,
                                                         wt, 512, 256, B * 512 * 256);
    k_gemm_bt<<<dim3(32, 2 * B), dim3(256), 0, stream>>>(wt, h3, hpT, B * 256, 4096, 512);
    k_agg<<<dim3(128, B, 1), dim3(256), 0, stream>>>(hpT, maskb,
        sA + bh * 4096, tA + bh * 4096, mA + bh * 4096, lA + bh * 4096,
        hC + bh * 256, (float*)0, 1536, 4096, 1, 0);
  }

  // ---- GroupNorm (in place on hC)
  k_gn_reduce<<<dim3(1024), dim3(256), 0, stream>>>(hC, gacc);
  k_gn_apply<<<dim3(3072), dim3(256), 0, stream>>>(hC, gacc, gn_w, gn_b, hC);

  // ---- conv2 (F=256): j-split Z=4, atomics straight into f32 d_out
  k_transpose<<<dim3(1536), dim3(256), 0, stream>>>(conv2_W, wt, 1536, 256, 1536 * 256);
  k_gemm_bt<<<dim3(32, 2), dim3(256), 0, stream>>>(wt, hC, hpT, 256, 4096, 1536);
  k_wa<<<dim3(12), dim3(256), 0, stream>>>(conv2_W, conv2_a, wab, 1536, 256, 3072);
  k_st2<<<dim3(1024, 1), dim3(256), 0, stream>>>(hC, wab, 1536, sA, tA);
  k_rowstats<<<dim3(1024, 1), dim3(256), 0, stream>>>(maskb, sA, tA, mA, lA);
  k_agg<<<dim3(128, 1, 4), dim3(256), 0, stream>>>(hpT, maskb, sA, tA, mA, lA,
                                                   (u16*)0, out, 256, 0, 0, 1);
  k_fin_f32<<<dim3(4096), dim3(256), 0, stream>>>(out, lA, 256);
}